// Round 1
// baseline (2769.237 us; speedup 1.0000x reference)
//
#include <hip/hip_runtime.h>

#define E_EDGES 320000
#define N_NODES 10000
#define F_DIM   128
#define C_DIM   384      // 3*F
#define NRBF_K  20
#define TILE    32       // edges per block-tile
#define TP      36       // padded LDS row stride (floats): 144B = 16B-aligned, odd/4 banks
#define PI_F    3.14159265358979323846f

// ---------------------------------------------------------------- sum(r^2) over all E*3
__global__ void sumsq_kernel(const float* __restrict__ r,
                             float* __restrict__ out) {
    __shared__ float red[4];
    int tid = blockIdx.x * blockDim.x + threadIdx.x;
    int stride = gridDim.x * blockDim.x;
    float acc = 0.f;
    for (int i = tid; i < E_EDGES * 3; i += stride) {
        float x = r[i];
        acc += x * x;
    }
    #pragma unroll
    for (int off = 32; off > 0; off >>= 1)
        acc += __shfl_down(acc, off, 64);
    int lane = threadIdx.x & 63;
    int wave = threadIdx.x >> 6;
    if (lane == 0) red[wave] = acc;
    __syncthreads();
    if (threadIdx.x == 0) {
        float s = red[0] + red[1] + red[2] + red[3];
        atomicAdd(out, s);
    }
}

// ---------------------------------------------------------------- main fused kernel
// 256 threads = 4 waves. Thread (lane=cl, wave=wv) computes a 6-col x 8-edge register
// tile: cols {2cl,2cl+1, +128, +256} (two complete sv/ss/sr triples), edges 8wv..8wv+7.
// Scatter goes straight from accumulators -> atomics (no split_sh exchange).
__global__ __launch_bounds__(256, 3) void main_kernel(
    const float* __restrict__ s,      // E x 128
    const float* __restrict__ r,      // E x 3
    const float* __restrict__ v,      // E x 3 x 128
    const int*   __restrict__ idx_i,  // E
    const float* __restrict__ W_phi,  // 128 x 384
    const float* __restrict__ b_phi,  // 384
    const float* __restrict__ W_w,    // 20 x 384
    const float* __restrict__ b_w,    // 384
    const float* __restrict__ sumsq,  // ws scalar: sum of r^2 (global Frobenius)
    float* __restrict__ out_v,        // N*3*128 (f32, zeroed, atomic accumulate)
    float* __restrict__ out_s)        // N*128
{
    __shared__ float s_tile[F_DIM][TP];      // [k][e]  (broadcast-read along e)
    __shared__ float rbf_sh[NRBF_K][TP];     // [n][e]
    __shared__ float orn_sh[TILE][3];
    __shared__ int   idx_sh[TILE];

    const int tid = threadIdx.x;
    const int cl  = tid & 63;        // float2-column index (cols 2cl,2cl+1)
    const int wv  = tid >> 6;        // wave id -> edge group
    const int e8  = wv * 8;
    const float inv_gn = rsqrtf(*sumsq);   // 1/||r||_F (matches jnp.linalg.norm(org_r))

    const float2* Wp2 = (const float2*)W_phi;   // rows of 192 float2
    const float2* Ww2 = (const float2*)W_w;
    const float2 bp0 = ((const float2*)b_phi)[cl];
    const float2 bp1 = ((const float2*)b_phi)[cl + 64];
    const float2 bp2 = ((const float2*)b_phi)[cl + 128];
    const float2 bw0 = ((const float2*)b_w)[cl];
    const float2 bw1 = ((const float2*)b_w)[cl + 64];
    const float2 bw2 = ((const float2*)b_w)[cl + 128];

    const int ntiles = E_EDGES / TILE;          // 10000 exact
    for (int t = blockIdx.x; t < ntiles; t += gridDim.x) {
        const int e0 = t * TILE;

        // ---- stage: s tile (coalesced global read, transposed LDS write) ----
        {
            const int k  = tid & 127;
            const int eb = tid >> 7;            // 0..1
            #pragma unroll
            for (int i = 0; i < 16; i++) {
                int e = eb + 2 * i;
                s_tile[k][e] = s[(size_t)(e0 + e) * F_DIM + k];
            }
        }
        // ---- stage: rbf (20 x 32) ----
        for (int q = tid; q < TILE * NRBF_K; q += 256) {
            int e = q / NRBF_K;
            int n = q - e * NRBF_K;
            float r0 = r[(e0 + e) * 3 + 0];
            float r1 = r[(e0 + e) * 3 + 1];
            float r2 = r[(e0 + e) * 3 + 2];
            float rn = sqrtf(r0 * r0 + r1 * r1 + r2 * r2);
            float arg  = (float)(n + 1) * (PI_F / 5.0f) * rn;
            float tv   = sinf(arg) / rn;
            rbf_sh[n][e] = (tv <= 5.0f) ? 0.5f * (cosf(PI_F * tv / 5.0f) + 1.0f)
                                        : 0.0f;
        }
        // ---- stage: org_rn + idx ----
        if (tid < TILE) {
            float r0 = r[(e0 + tid) * 3 + 0];
            float r1 = r[(e0 + tid) * 3 + 1];
            float r2 = r[(e0 + tid) * 3 + 2];
            orn_sh[tid][0] = r0 * inv_gn;
            orn_sh[tid][1] = r1 * inv_gn;
            orn_sh[tid][2] = r2 * inv_gn;
            idx_sh[tid] = idx_i[e0 + tid];
        }
        __syncthreads();

        // ---- register-tiled GEMMs: phi = s@W_phi + b ; w = rbf@W_w + b ----
        float2 ap0[8], ap1[8], ap2[8];   // phi acc: col-pairs {2cl}, {+128}, {+256}
        float2 aw0[8], aw1[8], aw2[8];   // w acc
        #pragma unroll
        for (int e = 0; e < 8; e++) {
            ap0[e] = bp0; ap1[e] = bp1; ap2[e] = bp2;
            aw0[e] = bw0; aw1[e] = bw1; aw2[e] = bw2;
        }

        #pragma unroll
        for (int n = 0; n < NRBF_K; n++) {
            float2 w0 = Ww2[n * 192 + cl];
            float2 w1 = Ww2[n * 192 + 64 + cl];
            float2 w2 = Ww2[n * 192 + 128 + cl];
            float sv[8];
            *(float4*)&sv[0] = *(const float4*)&rbf_sh[n][e8];
            *(float4*)&sv[4] = *(const float4*)&rbf_sh[n][e8 + 4];
            #pragma unroll
            for (int e = 0; e < 8; e++) {
                aw0[e].x += w0.x * sv[e]; aw0[e].y += w0.y * sv[e];
                aw1[e].x += w1.x * sv[e]; aw1[e].y += w1.y * sv[e];
                aw2[e].x += w2.x * sv[e]; aw2[e].y += w2.y * sv[e];
            }
        }

        for (int k = 0; k < F_DIM; k++) {
            float2 w0 = Wp2[k * 192 + cl];
            float2 w1 = Wp2[k * 192 + 64 + cl];
            float2 w2 = Wp2[k * 192 + 128 + cl];
            float sv[8];
            *(float4*)&sv[0] = *(const float4*)&s_tile[k][e8];
            *(float4*)&sv[4] = *(const float4*)&s_tile[k][e8 + 4];
            #pragma unroll
            for (int e = 0; e < 8; e++) {
                ap0[e].x += w0.x * sv[e]; ap0[e].y += w0.y * sv[e];
                ap1[e].x += w1.x * sv[e]; ap1[e].y += w1.y * sv[e];
                ap2[e].x += w2.x * sv[e]; ap2[e].y += w2.y * sv[e];
            }
        }

        // ---- scatter straight from registers ----
        #pragma unroll
        for (int e = 0; e < 8; e++) {
            const int ee  = e8 + e;
            const int idx = idx_sh[ee];
            const size_t vb = (size_t)(e0 + ee) * C_DIM + 2 * cl;
            float2 v0 = *(const float2*)&v[vb];
            float2 v1 = *(const float2*)&v[vb + 128];
            float2 v2 = *(const float2*)&v[vb + 256];
            float o0 = orn_sh[ee][0], o1 = orn_sh[ee][1], o2 = orn_sh[ee][2];
            float svx = ap0[e].x * aw0[e].x, svy = ap0[e].y * aw0[e].y;
            float ssx = ap1[e].x * aw1[e].x, ssy = ap1[e].y * aw1[e].y;
            float srx = ap2[e].x * aw2[e].x, sry = ap2[e].y * aw2[e].y;
            float* ovp = out_v + (size_t)idx * C_DIM + 2 * cl;
            atomicAdd(ovp,       svx * v0.x + srx * o0);
            atomicAdd(ovp + 1,   svy * v0.y + sry * o0);
            atomicAdd(ovp + 128, svx * v1.x + srx * o1);
            atomicAdd(ovp + 129, svy * v1.y + sry * o1);
            atomicAdd(ovp + 256, svx * v2.x + srx * o2);
            atomicAdd(ovp + 257, svy * v2.y + sry * o2);
            float* osp = out_s + (size_t)idx * F_DIM + 2 * cl;
            atomicAdd(osp,     ssx);
            atomicAdd(osp + 1, ssy);
        }
        __syncthreads();   // orn_sh/idx_sh/s_tile rewritten next iteration
    }
}

extern "C" void kernel_launch(void* const* d_in, const int* in_sizes, int n_in,
                              void* d_out, int out_size, void* d_ws, size_t ws_size,
                              hipStream_t stream) {
    const float* s     = (const float*)d_in[0];
    const float* r     = (const float*)d_in[1];
    const float* v     = (const float*)d_in[2];
    const int*   idx_i = (const int*)d_in[3];
    const float* W_phi = (const float*)d_in[4];
    const float* b_phi = (const float*)d_in[5];
    const float* W_w   = (const float*)d_in[6];
    const float* b_w   = (const float*)d_in[7];

    float* out   = (float*)d_out;               // [out_v (N*3*F)] [out_s (N*F)]
    float* sumsq = (float*)d_ws;                // one scalar (16B zeroed)
    const int NV = N_NODES * 3 * F_DIM;         // 3,840,000

    // d_out / d_ws are poisoned 0xAA before every launch — zero what we accumulate into.
    hipMemsetAsync(d_out, 0, (size_t)out_size * sizeof(float), stream);
    hipMemsetAsync(d_ws, 0, 16, stream);
    sumsq_kernel<<<512, 256, 0, stream>>>(r, sumsq);
    main_kernel<<<2048, 256, 0, stream>>>(s, r, v, idx_i, W_phi, b_phi, W_w, b_w,
                                          sumsq, out, out + NV);
}